// Round 6
// baseline (81.961 us; speedup 1.0000x reference)
//
#include <hip/hip_runtime.h>
#include <math.h>

// RoI "mod-7" max pooling (JAX reference-exact).
// x: (2, 512, 50, 50) fp32; rois: (R,5) fp32; out: (R, 512, 7, 7) fp32.
//
// Wave layout: lane = half*32 + dx (dx = window column slot, ftw <= 26);
// each wave runs TWO register chains -> 4 channels/wave (R3's empirically
// best balance: 4096 blocks = 16 blocks/CU absorbs per-roi cost variance).
//
// R5 = R3 grid + R4's maskless loads, unbundled:
//  - fast path (ftw >= 7): lane dx loads column cx = largest {dx-7k} < ftw.
//    Every load is a valid column of bin dx%7; duplicates are harmless under
//    max; the 2-shuffle fold over {j,j+7,j+14,j+21} is exact (col j+28 >= 28
//    > 26 >= ftw is never valid). Inner loop = load + fmax ONLY.
//  - slow path (ftw < 7, clipped rois): min-clamp + cndmask so empty
//    bin-columns stay -inf (-> 0 after pad clamp, segment_max semantics).
//  - XCD affinity: roi is the FASTEST grid dim, so one roi's 32 blocks have
//    linear ids = r + 128*cg -> same (id mod 8) XCD -> roi window cached in
//    one XCD's L2 instead of duplicated across all 8.

#define CH 512
#define IH 50
#define IW 50
#define PLANE (IH * IW)
#define NEG_INF (-__builtin_inff())

template <bool MASK>
__device__ __forceinline__ void run_rows(const float* __restrict__ b0,
                                         const float* __restrict__ b1,
                                         int full, int remh, bool colok,
                                         float (&acc0)[7], float (&acc1)[7]) {
  // Full super-rows: 14 independent loads per iteration, no masks (fast path).
  for (int s = 0; s < full; ++s) {
    const int off = s * 7 * IW;
#pragma unroll
    for (int i = 0; i < 7; ++i) {
      float v0 = b0[off + i * IW];
      float v1 = b1[off + i * IW];
      if (MASK) { v0 = colok ? v0 : NEG_INF; v1 = colok ? v1 : NEG_INF; }
      acc0[i] = fmaxf(acc0[i], v0);
      acc1[i] = fmaxf(acc1[i], v1);
    }
  }
  // Tail rows (0..6, wave-uniform count -> scalar skip branches; row fth may
  // lie past the allocation for the last channel, so rows can't be clamped).
  const int toff = full * 7 * IW;
#pragma unroll
  for (int i = 0; i < 7; ++i) {
    if (i < remh) {
      float v0 = b0[toff + i * IW];
      float v1 = b1[toff + i * IW];
      if (MASK) { v0 = colok ? v0 : NEG_INF; v1 = colok ? v1 : NEG_INF; }
      acc0[i] = fmaxf(acc0[i], v0);
      acc1[i] = fmaxf(acc1[i], v1);
    }
  }
}

__global__ __launch_bounds__(256) void roipool_kernel(
    const float* __restrict__ x, const float* __restrict__ rois,
    float* __restrict__ out) {
  const int r    = blockIdx.x;         // roi fastest -> XCD affinity
  const int cg   = blockIdx.y;         // 0..31 channel groups
  const int wave = threadIdx.x >> 6;   // 0..3
  const int lane = threadIdx.x & 63;
  const int half = lane >> 5;
  const int dx   = lane & 31;          // window column slot (ftw <= 26)

  // roi decode, forced wave-uniform (SGPRs -> scalar branches, scalar addrs).
  const float* rr = rois + r * 5;
  const int b  = __builtin_amdgcn_readfirstlane((int)rr[0]);
  const int y1 = __builtin_amdgcn_readfirstlane((int)rintf(rr[1] * 0.0625f));
  const int x1 = __builtin_amdgcn_readfirstlane((int)rintf(rr[2] * 0.0625f));
  const int y2 = __builtin_amdgcn_readfirstlane(min((int)rintf(rr[3] * 0.0625f), IH - 1));
  const int x2 = __builtin_amdgcn_readfirstlane(min((int)rintf(rr[4] * 0.0625f), IW - 1));
  const int fth  = y2 - y1 + 1;   // <= 26
  const int ftw  = x2 - x1 + 1;   // <= 26
  const int remh = fth % 7;
  const int remw = ftw % 7;
  const int full = fth / 7;       // 0..3

  // 4 channels per wave: 2 lane-halves x 2 register chains.
  const int cbase = (cg * 4 + wave) * 4 + half * 2;  // channels cbase, cbase+1

  // Fast-path column remap: cx = largest element of {dx-7k} below ftw.
  int cx = dx;
  cx = (cx >= ftw) ? cx - 7 : cx;
  cx = (cx >= ftw) ? cx - 7 : cx;
  cx = (cx >= ftw) ? cx - 7 : cx;
  cx = (cx >= ftw) ? cx - 7 : cx;
  const bool ftw_small = ftw < 7;       // wave-uniform -> scalar branch
  const bool colok = dx < ftw;
  const int  cxs   = min(dx, ftw - 1);  // slow-path in-bounds clamp

  const float* b0 = x + (size_t)(b * CH + cbase) * PLANE + (y1 * IW + x1)
                      + (ftw_small ? cxs : cx);
  const float* b1 = b0 + PLANE;

  float acc0[7], acc1[7];
#pragma unroll
  for (int i = 0; i < 7; ++i) { acc0[i] = NEG_INF; acc1[i] = NEG_INF; }

  if (!ftw_small) run_rows<false>(b0, b1, full, remh, true,  acc0, acc1);
  else            run_rows<true >(b0, b1, full, remh, colok, acc0, acc1);

  // Column fold: lane j (<7 per half) <- max over {j, j+7, j+14, j+21}.
#pragma unroll
  for (int i = 0; i < 7; ++i) {
    float a0 = acc0[i], a1 = acc1[i];
    a0 = fmaxf(a0, __shfl_down(a0, 7, 64));
    a1 = fmaxf(a1, __shfl_down(a1, 7, 64));
    a0 = fmaxf(a0, __shfl_down(a0, 14, 64));
    a1 = fmaxf(a1, __shfl_down(a1, 14, 64));
    acc0[i] = a0;
    acc1[i] = a1;
  }

  // Pad-clamp (bins beyond remh/remw -> max(val, 0)) + store.
  if (dx < 7) {
    const int j = dx;
    const bool padc = (remw != 0) && (j >= remw);
    float* o0 = out + (size_t)(r * CH + cbase) * 49 + j;
    float* o1 = o0 + 49;
#pragma unroll
    for (int i = 0; i < 7; ++i) {
      float v0 = acc0[i], v1 = acc1[i];
      const bool padr = (remh != 0) && (i >= remh);
      if (padr | padc) { v0 = fmaxf(v0, 0.0f); v1 = fmaxf(v1, 0.0f); }
      o0[i * 7] = v0;
      o1[i * 7] = v1;
    }
  }
}

extern "C" void kernel_launch(void* const* d_in, const int* in_sizes, int n_in,
                              void* d_out, int out_size, void* d_ws, size_t ws_size,
                              hipStream_t stream) {
  const float* x    = (const float*)d_in[0];
  const float* rois = (const float*)d_in[1];
  float* out        = (float*)d_out;
  const int R = in_sizes[1] / 5;  // 128

  dim3 grid(R, 32);   // roi fastest (XCD affinity) x 32 channel-groups
  dim3 block(256);    // 4 waves; each wave = 4 channels
  roipool_kernel<<<grid, block, 0, stream>>>(x, rois, out);
}

// Round 7
// 75.901 us; speedup vs baseline: 1.0798x; 1.0798x over previous
//
#include <hip/hip_runtime.h>
#include <math.h>

// RoI "mod-7" max pooling (JAX reference-exact).
// x: (2, 512, 50, 50) fp32; rois: (R,5) fp32; out: (R, 512, 7, 7) fp32.
//
// == R6 = R3's grid (best measured: 71.0 us) + maskless loads ONLY ==
// Grid: blockIdx.x = channel-group (fastest), blockIdx.y = roi. Consecutive
// blocks share a roi and read consecutive channel planes / write contiguous
// output -> best L2 locality (roi-fastest ordering measured -11 us WORSE).
//
// Wave layout: lane = half*32 + dx (window column slot, ftw <= 26); two
// register chains per wave -> 4 channels/wave, 16384 waves, 4096 blocks.
//
// Maskless fast path (ftw >= 7): lane dx loads column cx = largest element
// of {dx, dx-7, dx-14, dx-21} below ftw (computed once). Every load is then
// a valid column of bin dx%7; duplicates are harmless under max; the
// 2-shuffle fold over {j, j+7, j+14, j+21} is exact (col j+28 >= 28 > 26 >=
// ftw never valid). Inner loop = load + fmax ONLY (no per-load cndmask).
// Slow path (ftw < 7: empty bin-columns exist): clamp + cndmask keeps empty
// bins at -inf (-> 0 after pad clamp, matching segment_max semantics).

#define CH 512
#define IH 50
#define IW 50
#define PLANE (IH * IW)
#define NEG_INF (-__builtin_inff())

template <bool MASK>
__device__ __forceinline__ void run_rows(const float* __restrict__ b0,
                                         const float* __restrict__ b1,
                                         int full, int remh, bool colok,
                                         float (&acc0)[7], float (&acc1)[7]) {
  // Full super-rows: 14 independent loads per iteration.
  for (int s = 0; s < full; ++s) {
    const int off = s * 7 * IW;
#pragma unroll
    for (int i = 0; i < 7; ++i) {
      float v0 = b0[off + i * IW];
      float v1 = b1[off + i * IW];
      if (MASK) { v0 = colok ? v0 : NEG_INF; v1 = colok ? v1 : NEG_INF; }
      acc0[i] = fmaxf(acc0[i], v0);
      acc1[i] = fmaxf(acc1[i], v1);
    }
  }
  // Tail rows (0..6, wave-uniform count -> scalar skip branches; row fth may
  // lie past the allocation for the last channel, so rows can't be clamped).
  const int toff = full * 7 * IW;
#pragma unroll
  for (int i = 0; i < 7; ++i) {
    if (i < remh) {
      float v0 = b0[toff + i * IW];
      float v1 = b1[toff + i * IW];
      if (MASK) { v0 = colok ? v0 : NEG_INF; v1 = colok ? v1 : NEG_INF; }
      acc0[i] = fmaxf(acc0[i], v0);
      acc1[i] = fmaxf(acc1[i], v1);
    }
  }
}

__global__ __launch_bounds__(256) void roipool_kernel(
    const float* __restrict__ x, const float* __restrict__ rois,
    float* __restrict__ out) {
  const int cg   = blockIdx.x;         // channel group fastest (R3 layout)
  const int r    = blockIdx.y;         // roi
  const int wave = threadIdx.x >> 6;   // 0..3
  const int lane = threadIdx.x & 63;
  const int half = lane >> 5;
  const int dx   = lane & 31;          // window column slot (ftw <= 26)

  // roi decode, forced wave-uniform (SGPRs -> scalar branches, scalar addrs).
  const float* rr = rois + r * 5;
  const int b  = __builtin_amdgcn_readfirstlane((int)rr[0]);
  const int y1 = __builtin_amdgcn_readfirstlane((int)rintf(rr[1] * 0.0625f));
  const int x1 = __builtin_amdgcn_readfirstlane((int)rintf(rr[2] * 0.0625f));
  const int y2 = __builtin_amdgcn_readfirstlane(min((int)rintf(rr[3] * 0.0625f), IH - 1));
  const int x2 = __builtin_amdgcn_readfirstlane(min((int)rintf(rr[4] * 0.0625f), IW - 1));
  const int fth  = y2 - y1 + 1;   // <= 26
  const int ftw  = x2 - x1 + 1;   // <= 26
  const int remh = fth % 7;
  const int remw = ftw % 7;
  const int full = fth / 7;       // 0..3

  // 4 channels per wave: 2 lane-halves x 2 register chains.
  const int cbase = (cg * 4 + wave) * 4 + half * 2;  // channels cbase, cbase+1

  // Fast-path column remap: cx = largest element of {dx-7k} below ftw.
  int cx = dx;
  cx = (cx >= ftw) ? cx - 7 : cx;
  cx = (cx >= ftw) ? cx - 7 : cx;
  cx = (cx >= ftw) ? cx - 7 : cx;
  cx = (cx >= ftw) ? cx - 7 : cx;
  const bool ftw_small = ftw < 7;       // wave-uniform -> scalar branch
  const bool colok = dx < ftw;
  const int  cxs   = min(dx, ftw - 1);  // slow-path in-bounds clamp

  const float* b0 = x + (size_t)(b * CH + cbase) * PLANE + (y1 * IW + x1)
                      + (ftw_small ? cxs : cx);
  const float* b1 = b0 + PLANE;

  float acc0[7], acc1[7];
#pragma unroll
  for (int i = 0; i < 7; ++i) { acc0[i] = NEG_INF; acc1[i] = NEG_INF; }

  if (!ftw_small) run_rows<false>(b0, b1, full, remh, true,  acc0, acc1);
  else            run_rows<true >(b0, b1, full, remh, colok, acc0, acc1);

  // Column fold: lane j (<7 per half) <- max over {j, j+7, j+14, j+21}.
#pragma unroll
  for (int i = 0; i < 7; ++i) {
    float a0 = acc0[i], a1 = acc1[i];
    a0 = fmaxf(a0, __shfl_down(a0, 7, 64));
    a1 = fmaxf(a1, __shfl_down(a1, 7, 64));
    a0 = fmaxf(a0, __shfl_down(a0, 14, 64));
    a1 = fmaxf(a1, __shfl_down(a1, 14, 64));
    acc0[i] = a0;
    acc1[i] = a1;
  }

  // Pad-clamp (bins beyond remh/remw -> max(val, 0)) + store.
  if (dx < 7) {
    const int j = dx;
    const bool padc = (remw != 0) && (j >= remw);
    float* o0 = out + (size_t)(r * CH + cbase) * 49 + j;
    float* o1 = o0 + 49;
#pragma unroll
    for (int i = 0; i < 7; ++i) {
      float v0 = acc0[i], v1 = acc1[i];
      const bool padr = (remh != 0) && (i >= remh);
      if (padr | padc) { v0 = fmaxf(v0, 0.0f); v1 = fmaxf(v1, 0.0f); }
      o0[i * 7] = v0;
      o1[i * 7] = v1;
    }
  }
}

extern "C" void kernel_launch(void* const* d_in, const int* in_sizes, int n_in,
                              void* d_out, int out_size, void* d_ws, size_t ws_size,
                              hipStream_t stream) {
  const float* x    = (const float*)d_in[0];
  const float* rois = (const float*)d_in[1];
  float* out        = (float*)d_out;
  const int R = in_sizes[1] / 5;  // 128

  dim3 grid(32, R);   // cg fastest x roi (R3's best-measured ordering)
  dim3 block(256);    // 4 waves; each wave = 4 channels
  roipool_kernel<<<grid, block, 0, stream>>>(x, rois, out);
}